// Round 11
// baseline (931.418 us; speedup 1.0000x reference)
//
#include <hip/hip_runtime.h>
#include <hip/hip_bf16.h>

#define D_IN 64
#define D_EMB 128
#define GI 192           // D_IN + D_EMB
#define H1 32
#define H2 8

typedef __attribute__((ext_vector_type(8))) short bf16x8;
typedef __attribute__((ext_vector_type(4))) float f32x4;

__device__ __forceinline__ unsigned short f2bf(float f) {
    unsigned int u = __float_as_uint(f);
    return (unsigned short)((u + 0x7fffu + ((u >> 16) & 1u)) >> 16);
}
__device__ __forceinline__ float bflo(unsigned int u) { return __uint_as_float(u << 16); }
__device__ __forceinline__ float bfhi(unsigned int u) { return __uint_as_float(u & 0xffff0000u); }
__device__ __forceinline__ unsigned int pk2(unsigned short a, unsigned short b) {
    return (unsigned int)a | ((unsigned int)b << 16);
}

// ---------------------------------------------------------------------------
// CSR build, XCD-partitioned (round-3 notes: merges partial-line writes in L2)
// ---------------------------------------------------------------------------
__global__ __launch_bounds__(256) void hist_part_k(const int* __restrict__ dst, int* __restrict__ cnt,
                                                   int E, int N8) {
    int p = blockIdx.x & 7;
    int base = (blockIdx.x >> 3) * 1024;
    int lo = p * N8, hi = lo + N8;
    #pragma unroll
    for (int t = 0; t < 4; ++t) {
        int e = base + t * 256 + threadIdx.x;
        if (e < E) {
            int d = dst[e];
            if (d >= lo && d < hi) atomicAdd(&cnt[d], 1);
        }
    }
}

__global__ __launch_bounds__(256) void scan1_k(const int* __restrict__ cnt, int* __restrict__ loc,
                                               int* __restrict__ bsum, int N) {
    __shared__ int s[256];
    int tid = threadIdx.x;
    int i = blockIdx.x * 256 + tid;
    int v = (i < N) ? cnt[i] : 0;
    s[tid] = v;
    __syncthreads();
    #pragma unroll
    for (int off = 1; off < 256; off <<= 1) {
        int u = (tid >= off) ? s[tid - off] : 0;
        __syncthreads();
        s[tid] += u;
        __syncthreads();
    }
    int incl = s[tid];
    if (i < N) loc[i] = incl - v;
    if (tid == 255) bsum[blockIdx.x] = incl;
}

__global__ __launch_bounds__(512) void scan2_k(int* __restrict__ bsum, int NB) {
    __shared__ int s[512];
    int tid = threadIdx.x;
    int v = (tid < NB) ? bsum[tid] : 0;
    s[tid] = v;
    __syncthreads();
    #pragma unroll
    for (int off = 1; off < 512; off <<= 1) {
        int u = (tid >= off) ? s[tid - off] : 0;
        __syncthreads();
        s[tid] += u;
        __syncthreads();
    }
    if (tid < NB) bsum[tid] = s[tid] - v;
}

__global__ __launch_bounds__(256) void scan3_k(int* __restrict__ rp, const int* __restrict__ bsum,
                                               int* __restrict__ cursor, int N, int E) {
    int i = blockIdx.x * 256 + threadIdx.x;
    if (i < N) {
        int r = rp[i] + bsum[i >> 8];
        rp[i] = r;
        cursor[i] = r;
    } else if (i == N) {
        rp[N] = E;
    }
}

__global__ __launch_bounds__(256) void scatter_part_k(const int* __restrict__ src, const int* __restrict__ dst,
                                                      int* __restrict__ cursor, int* __restrict__ csr,
                                                      int E, int N8) {
    int p = blockIdx.x & 7;
    int base = (blockIdx.x >> 3) * 1024;
    int lo = p * N8, hi = lo + N8;
    #pragma unroll
    for (int t = 0; t < 4; ++t) {
        int e = base + t * 256 + threadIdx.x;
        if (e < E) {
            int d = dst[e];
            if (d >= lo && d < hi) {
                int s = src[e];
                int pos = atomicAdd(&cursor[d], 1);
                csr[pos] = s;
            }
        }
    }
}

// ---------------------------------------------------------------------------
// Conversions / weight fragment prep
// ---------------------------------------------------------------------------
__global__ __launch_bounds__(256) void xcvt_k(const float* __restrict__ x, unsigned short* __restrict__ xb,
                                              int total4) {
    int i = blockIdx.x * 256 + threadIdx.x;
    if (i < total4) {
        float4 v = ((const float4*)x)[i];
        ((uint2*)xb)[i] = make_uint2(pk2(f2bf(v.x), f2bf(v.y)), pk2(f2bf(v.z), f2bf(v.w)));
    }
}

__global__ __launch_bounds__(256) void wfrag_all_k(
    const float* __restrict__ W_in, const float* __restrict__ mlp_W1, const float* __restrict__ mlp_W2,
    const float* __restrict__ graph_W, const float* __restrict__ out_W,
    unsigned short* __restrict__ wf_in, unsigned short* __restrict__ wf_w1,
    unsigned short* __restrict__ wf_w2, unsigned short* __restrict__ wf_graph,
    unsigned short* __restrict__ wf_out) {
    int idx = blockIdx.x * 256 + threadIdx.x;
    const float* src;
    unsigned short* dst;
    int local;
    if (idx < 8192) { src = W_in; dst = wf_in; local = idx; }
    else if (idx < 81920) { int t = idx - 8192; int l = t / 24576; local = t - l * 24576;
                            src = mlp_W1 + (size_t)l * 24576; dst = wf_w1 + (size_t)l * 24576; }
    else if (idx < 131072) { int t = idx - 81920; int l = t / 16384; local = t - l * 16384;
                             src = mlp_W2 + (size_t)l * 16384; dst = wf_w2 + (size_t)l * 16384; }
    else if (idx < 147456) { local = idx - 131072; src = graph_W; dst = wf_graph; }
    else { local = idx - 147456; src = out_W; dst = wf_out; }
    int k = local >> 7, c = local & 127;
    dst[(((size_t)(k >> 3) * 128) + c) * 8 + (k & 7)] = f2bf(src[local]);
}

// ---------------------------------------------------------------------------
// x aggregation (layer-invariant), bf16 output
// ---------------------------------------------------------------------------
__global__ __launch_bounds__(256) void agg64b_k(const unsigned short* __restrict__ xb,
                                                const int* __restrict__ rp, const int* __restrict__ cs,
                                                unsigned short* __restrict__ outb, int N) {
    int n = blockIdx.x * 8 + (threadIdx.x >> 5);
    int lane = threadIdx.x & 31;
    if (n >= N) return;
    int bg = rp[n], e = rp[n + 1];
    const unsigned int* x2 = (const unsigned int*)xb;
    float sx = 0.f, sy = 0.f;
    int j = bg;
    for (; j + 3 < e; j += 4) {
        unsigned int v0 = x2[(size_t)cs[j] * 32 + lane];
        unsigned int v1 = x2[(size_t)cs[j + 1] * 32 + lane];
        unsigned int v2 = x2[(size_t)cs[j + 2] * 32 + lane];
        unsigned int v3 = x2[(size_t)cs[j + 3] * 32 + lane];
        sx += bflo(v0) + bflo(v1) + bflo(v2) + bflo(v3);
        sy += bfhi(v0) + bfhi(v1) + bfhi(v2) + bfhi(v3);
    }
    for (; j < e; ++j) {
        unsigned int v = x2[(size_t)cs[j] * 32 + lane];
        sx += bflo(v);
        sy += bfhi(v);
    }
    ((unsigned int*)outb)[(size_t)n * 32 + lane] = pk2(f2bf(sx), f2bf(sy));
}

// ---------------------------------------------------------------------------
// Precompute zx_l = bf16((1+eps_l)*x + aggx) for all 3 layers ([N][64] each)
// Same fmaf/f2bf as before -> bit-identical values.
// ---------------------------------------------------------------------------
__global__ __launch_bounds__(256) void zxcvt_k(const unsigned short* __restrict__ xb,
                                               const unsigned short* __restrict__ aggxb,
                                               const float* __restrict__ eps,
                                               unsigned short* __restrict__ zx0,
                                               unsigned short* __restrict__ zx1,
                                               unsigned short* __restrict__ zx2, int total2) {
    int i = blockIdx.x * 256 + threadIdx.x;
    if (i >= total2) return;
    unsigned int xv = ((const unsigned int*)xb)[i];
    unsigned int av = ((const unsigned int*)aggxb)[i];
    float xl = bflo(xv), xh = bfhi(xv), al = bflo(av), ah = bfhi(av);
    float e0 = 1.0f + eps[0], e1 = 1.0f + eps[1], e2 = 1.0f + eps[2];
    ((unsigned int*)zx0)[i] = pk2(f2bf(fmaf(e0, xl, al)), f2bf(fmaf(e0, xh, ah)));
    ((unsigned int*)zx1)[i] = pk2(f2bf(fmaf(e1, xl, al)), f2bf(fmaf(e1, xh, ah)));
    ((unsigned int*)zx2)[i] = pk2(f2bf(fmaf(e2, xl, al)), f2bf(fmaf(e2, xh, ah)));
}

// ---------------------------------------------------------------------------
// h aggregation + GIN-z fold: zh = bf16((1+eps)*h[n] + sum_{neighbors} h)
// ---------------------------------------------------------------------------
__global__ __launch_bounds__(256) void aggz_k(const unsigned short* __restrict__ hb,
                                              const int* __restrict__ rp, const int* __restrict__ cs,
                                              const float* __restrict__ epsp,
                                              unsigned short* __restrict__ zh, int N) {
    int w = threadIdx.x >> 6, lane = threadIdx.x & 63;
    int n = blockIdx.x * 4 + w;
    if (n >= N) return;
    float es = 1.0f + epsp[0];
    int bg = rp[n], e = rp[n + 1];
    const unsigned int* h2 = (const unsigned int*)hb;
    float sx = 0.f, sy = 0.f;
    int j = bg;
    for (; j + 3 < e; j += 4) {
        unsigned int v0 = h2[(size_t)cs[j] * 64 + lane];
        unsigned int v1 = h2[(size_t)cs[j + 1] * 64 + lane];
        unsigned int v2 = h2[(size_t)cs[j + 2] * 64 + lane];
        unsigned int v3 = h2[(size_t)cs[j + 3] * 64 + lane];
        sx += bflo(v0) + bflo(v1) + bflo(v2) + bflo(v3);
        sy += bfhi(v0) + bfhi(v1) + bfhi(v2) + bfhi(v3);
    }
    for (; j < e; ++j) {
        unsigned int v = h2[(size_t)cs[j] * 64 + lane];
        sx += bflo(v);
        sy += bfhi(v);
    }
    unsigned int hv = h2[(size_t)n * 64 + lane];
    sx = fmaf(es, bflo(hv), sx);
    sy = fmaf(es, bfhi(hv), sy);
    ((unsigned int*)zh)[(size_t)n * 64 + lane] = pk2(f2bf(sx), f2bf(sy));
}

// ---------------------------------------------------------------------------
// Cross-wave LayerNorm epilogue for a 128x128 tile held as 4x4 16x16 C-frags.
// ---------------------------------------------------------------------------
template <int RELU, int ELU>
__device__ __forceinline__ void ln_epilogue(
    f32x4 (&acc)[4][4], const float* __restrict__ bias,
    const float* __restrict__ g, const float* __restrict__ b,
    unsigned short* __restrict__ out,
    int rowBase, int wr, int wc, int lg, int l15, int wh,
    float* rsum, float* rsq, int N) {
    float bv[4], gv[4], bbv[4];
    #pragma unroll
    for (int cb = 0; cb < 4; ++cb) {
        int col = wc + cb * 16 + l15;
        bv[cb] = bias[col];
        gv[cb] = g[col];
        bbv[cb] = b[col];
    }
    float ps[4][4], pq[4][4];
    #pragma unroll
    for (int rb = 0; rb < 4; ++rb)
        #pragma unroll
        for (int q = 0; q < 4; ++q) {
            float s = 0.f, sq = 0.f;
            #pragma unroll
            for (int cb = 0; cb < 4; ++cb) {
                float v = acc[rb][cb][q] + bv[cb];
                if (RELU) v = fmaxf(v, 0.f);
                s += v;
                sq += v * v;
            }
            ps[rb][q] = s;
            pq[rb][q] = sq;
        }
    #pragma unroll
    for (int m = 1; m < 16; m <<= 1) {
        #pragma unroll
        for (int rb = 0; rb < 4; ++rb)
            #pragma unroll
            for (int q = 0; q < 4; ++q) {
                ps[rb][q] += __shfl_xor(ps[rb][q], m, 64);
                pq[rb][q] += __shfl_xor(pq[rb][q], m, 64);
            }
    }
    if (l15 == 0) {
        #pragma unroll
        for (int rb = 0; rb < 4; ++rb)
            #pragma unroll
            for (int q = 0; q < 4; ++q) {
                int row = wr + rb * 16 + lg * 4 + q;
                rsum[wh * 128 + row] = ps[rb][q];
                rsq[wh * 128 + row] = pq[rb][q];
            }
    }
    __syncthreads();
    #pragma unroll
    for (int rb = 0; rb < 4; ++rb)
        #pragma unroll
        for (int q = 0; q < 4; ++q) {
            int row = wr + rb * 16 + lg * 4 + q;
            float st = rsum[row] + rsum[128 + row];
            float sqt = rsq[row] + rsq[128 + row];
            float mu = st * (1.f / 128.f);
            float var = sqt * (1.f / 128.f) - mu * mu;
            float rs = rsqrtf(var + 1e-5f);
            int grow = rowBase + row;
            if (grow < N) {
                #pragma unroll
                for (int cb = 0; cb < 4; ++cb) {
                    float v = acc[rb][cb][q] + bv[cb];
                    if (RELU) v = fmaxf(v, 0.f);
                    float y = (v - mu) * rs * gv[cb] + bbv[cb];
                    if (ELU) y = y > 0.f ? y : expm1f(y);
                    out[(size_t)grow * D_EMB + wc + cb * 16 + l15] = f2bf(y);
                }
            }
        }
}

// ---------------------------------------------------------------------------
// Encoder GEMM, direct A-fragments (no LDS, no barriers):
// hb = relu(xb @ W_in + b_in), K=64
// ---------------------------------------------------------------------------
__global__ __launch_bounds__(256) void enc_gemm_k(
    const unsigned short* __restrict__ Abf, const unsigned short* __restrict__ Wf,
    const float* __restrict__ bias, unsigned short* __restrict__ C, int N) {
    const int tid = threadIdx.x;
    const int wid = tid >> 6, lane = tid & 63;
    const int l15 = lane & 15, lg = lane >> 4;
    const int rowBase = blockIdx.x * 128;
    const int wr = (wid >> 1) * 64, wc = (wid & 1) * 64;
    f32x4 zero = {0.f, 0.f, 0.f, 0.f};
    f32x4 acc[4][4];
    #pragma unroll
    for (int i = 0; i < 4; ++i)
        #pragma unroll
        for (int j = 0; j < 4; ++j) acc[i][j] = zero;
    const unsigned short* ap[4];
    #pragma unroll
    for (int rb = 0; rb < 4; ++rb)
        ap[rb] = Abf + (size_t)min(rowBase + wr + rb * 16 + l15, N - 1) * D_IN;

    for (int k0 = 0; k0 < D_IN; k0 += 32) {
        const int G = (k0 >> 3) + lg;
        bf16x8 bfr[4];
        #pragma unroll
        for (int cb = 0; cb < 4; ++cb)
            bfr[cb] = *(const bf16x8*)&Wf[(((size_t)G * 128) + wc + cb * 16 + l15) * 8];
        #pragma unroll
        for (int rb = 0; rb < 4; ++rb) {
            bf16x8 afr = *(const bf16x8*)(ap[rb] + G * 8);
            #pragma unroll
            for (int cb = 0; cb < 4; ++cb)
                acc[rb][cb] = __builtin_amdgcn_mfma_f32_16x16x32_bf16(afr, bfr[cb], acc[rb][cb], 0, 0, 0);
        }
    }
    #pragma unroll
    for (int cb = 0; cb < 4; ++cb) {
        int col = wc + cb * 16 + l15;
        float bvv = bias[col];
        #pragma unroll
        for (int rb = 0; rb < 4; ++rb)
            #pragma unroll
            for (int q = 0; q < 4; ++q) {
                int row = rowBase + wr + rb * 16 + lg * 4 + q;
                if (row < N) C[(size_t)row * D_EMB + col] = f2bf(fmaxf(acc[rb][cb][q] + bvv, 0.f));
            }
    }
}

// ---------------------------------------------------------------------------
// Fused GIN layer, direct A-fragments for GEMM1 (zxl k<64, zh k>=64; no
// staging, no barriers). GEMM2 via T1 in LDS, split into two 64-col chunks
// (16 KB). Then LN+ELU.
// ---------------------------------------------------------------------------
__global__ __launch_bounds__(256) void gin_layer_k(
    const unsigned short* __restrict__ zxl, const unsigned short* __restrict__ zhb,
    const unsigned short* __restrict__ W1f, const float* __restrict__ b1,
    const unsigned short* __restrict__ W2f, const float* __restrict__ b2,
    const float* __restrict__ lng, const float* __restrict__ lnb,
    unsigned short* __restrict__ hbo, int N) {
    __shared__ unsigned short T1[8 * 128 * 8];  // 16 KB (one 64-col chunk)
    __shared__ float rsum[2 * 128];
    __shared__ float rsq[2 * 128];

    const int tid = threadIdx.x;
    const int wid = tid >> 6, lane = tid & 63;
    const int l15 = lane & 15, lg = lane >> 4;
    const int rowBase = blockIdx.x * 128;
    const int wr = (wid >> 1) * 64, wc = (wid & 1) * 64;
    const int wh = wid & 1;

    f32x4 zero = {0.f, 0.f, 0.f, 0.f};
    f32x4 acc[4][4];
    #pragma unroll
    for (int i = 0; i < 4; ++i)
        #pragma unroll
        for (int j = 0; j < 4; ++j) acc[i][j] = zero;

    const unsigned short* axp[4];  // zx rows (64 wide)
    const unsigned short* ahp[4];  // zh rows (128 wide)
    #pragma unroll
    for (int rb = 0; rb < 4; ++rb) {
        int ar = min(rowBase + wr + rb * 16 + l15, N - 1);
        axp[rb] = zxl + (size_t)ar * D_IN;
        ahp[rb] = zhb + (size_t)ar * D_EMB;
    }

    // ---- GEMM1, k < 64 (zx part) ----
    for (int k0 = 0; k0 < D_IN; k0 += 32) {
        const int G = (k0 >> 3) + lg;
        bf16x8 bfr[4];
        #pragma unroll
        for (int cb = 0; cb < 4; ++cb)
            bfr[cb] = *(const bf16x8*)&W1f[(((size_t)G * 128) + wc + cb * 16 + l15) * 8];
        #pragma unroll
        for (int rb = 0; rb < 4; ++rb) {
            bf16x8 afr = *(const bf16x8*)(axp[rb] + G * 8);
            #pragma unroll
            for (int cb = 0; cb < 4; ++cb)
                acc[rb][cb] = __builtin_amdgcn_mfma_f32_16x16x32_bf16(afr, bfr[cb], acc[rb][cb], 0, 0, 0);
        }
    }
    // ---- GEMM1, k >= 64 (zh part) ----
    for (int k0 = D_IN; k0 < GI; k0 += 32) {
        const int G = (k0 >> 3) + lg;
        const int ZG = ((k0 - D_IN) >> 3) + lg;
        bf16x8 bfr[4];
        #pragma unroll
        for (int cb = 0; cb < 4; ++cb)
            bfr[cb] = *(const bf16x8*)&W1f[(((size_t)G * 128) + wc + cb * 16 + l15) * 8];
        #pragma unroll
        for (int rb = 0; rb < 4; ++rb) {
            bf16x8 afr = *(const bf16x8*)(ahp[rb] + ZG * 8);
            #pragma unroll
            for (int cb = 0; cb < 4; ++cb)
                acc[rb][cb] = __builtin_amdgcn_mfma_f32_16x16x32_bf16(afr, bfr[cb], acc[rb][cb], 0, 0, 0);
        }
    }

    // ---- GEMM2 in two 64-col chunks of t1 ----
    f32x4 acc2[4][4];
    #pragma unroll
    for (int i = 0; i < 4; ++i)
        #pragma unroll
        for (int j = 0; j < 4; ++j) acc2[i][j] = zero;

    #pragma unroll
    for (int c = 0; c < 2; ++c) {
        if (c) __syncthreads();        // chunk-0 reads complete before overwrite
        if (wc == c * 64) {
            #pragma unroll
            for (int cb = 0; cb < 4; ++cb) {
                int col = wc + cb * 16 + l15;
                int tcol = col - c * 64;
                float bvv = b1[col];
                #pragma unroll
                for (int rb = 0; rb < 4; ++rb)
                    #pragma unroll
                    for (int q = 0; q < 4; ++q) {
                        int row = wr + rb * 16 + lg * 4 + q;
                        float v = fmaxf(acc[rb][cb][q] + bvv, 0.f);
                        T1[(((size_t)(tcol >> 3) * 128) + row) * 8 + (tcol & 7)] = f2bf(v);
                    }
            }
        }
        __syncthreads();
        for (int k0 = c * 64; k0 < c * 64 + 64; k0 += 32) {
            const int G = (k0 >> 3) + lg;
            const int TG = G - c * 8;
            bf16x8 bfr[4];
            #pragma unroll
            for (int cb = 0; cb < 4; ++cb)
                bfr[cb] = *(const bf16x8*)&W2f[(((size_t)G * 128) + wc + cb * 16 + l15) * 8];
            #pragma unroll
            for (int rb = 0; rb < 4; ++rb) {
                bf16x8 afr = *(const bf16x8*)&T1[(((size_t)TG * 128) + wr + rb * 16 + l15) * 8];
                #pragma unroll
                for (int cb = 0; cb < 4; ++cb)
                    acc2[rb][cb] = __builtin_amdgcn_mfma_f32_16x16x32_bf16(afr, bfr[cb], acc2[rb][cb], 0, 0, 0);
            }
        }
    }

    ln_epilogue<0, 1>(acc2, b2, lng, lnb, hbo, rowBase, wr, wc, lg, l15, wh, rsum, rsq, N);
}

// ---------------------------------------------------------------------------
// Dual FC+LN, direct A-fragments (hin read once per lane from L1/L2):
// graph branch -> outG, node branch -> outN
// ---------------------------------------------------------------------------
__global__ __launch_bounds__(256) void fc2_k(
    const unsigned short* __restrict__ Abf,
    const unsigned short* __restrict__ WfG, const float* __restrict__ biasG,
    const float* __restrict__ gG, const float* __restrict__ bG, unsigned short* __restrict__ outG,
    const unsigned short* __restrict__ WfN, const float* __restrict__ biasN,
    const float* __restrict__ gN, const float* __restrict__ bN, unsigned short* __restrict__ outN,
    int N) {
    __shared__ float rsum[2 * 128];
    __shared__ float rsq[2 * 128];
    const int tid = threadIdx.x;
    const int wid = tid >> 6, lane = tid & 63;
    const int l15 = lane & 15, lg = lane >> 4;
    const int rowBase = blockIdx.x * 128;
    const int wr = (wid >> 1) * 64, wc = (wid & 1) * 64;
    const int wh = wid & 1;
    f32x4 zero = {0.f, 0.f, 0.f, 0.f};
    f32x4 accG[4][4], accN[4][4];
    #pragma unroll
    for (int i = 0; i < 4; ++i)
        #pragma unroll
        for (int j = 0; j < 4; ++j) { accG[i][j] = zero; accN[i][j] = zero; }
    const unsigned short* ap[4];
    #pragma unroll
    for (int rb = 0; rb < 4; ++rb)
        ap[rb] = Abf + (size_t)min(rowBase + wr + rb * 16 + l15, N - 1) * D_EMB;

    for (int k0 = 0; k0 < D_EMB; k0 += 32) {
        const int G = (k0 >> 3) + lg;
        bf16x8 bfrG[4], bfrN[4];
        #pragma unroll
        for (int cb = 0; cb < 4; ++cb) {
            bfrG[cb] = *(const bf16x8*)&WfG[(((size_t)G * 128) + wc + cb * 16 + l15) * 8];
            bfrN[cb] = *(const bf16x8*)&WfN[(((size_t)G * 128) + wc + cb * 16 + l15) * 8];
        }
        #pragma unroll
        for (int rb = 0; rb < 4; ++rb) {
            bf16x8 afr = *(const bf16x8*)(ap[rb] + G * 8);
            #pragma unroll
            for (int cb = 0; cb < 4; ++cb) {
                accG[rb][cb] = __builtin_amdgcn_mfma_f32_16x16x32_bf16(afr, bfrG[cb], accG[rb][cb], 0, 0, 0);
                accN[rb][cb] = __builtin_amdgcn_mfma_f32_16x16x32_bf16(afr, bfrN[cb], accN[rb][cb], 0, 0, 0);
            }
        }
    }
    ln_epilogue<1, 0>(accG, biasG, gG, bG, outG, rowBase, wr, wc, lg, l15, wh, rsum, rsq, N);
    __syncthreads();   // rsum/rsq reuse barrier between the two epilogues
    ln_epilogue<1, 0>(accN, biasN, gN, bN, outN, rowBase, wr, wc, lg, l15, wh, rsum, rsq, N);
}

// ---------------------------------------------------------------------------
// Graph segment bounds, then 8-way-split mean pool
// ---------------------------------------------------------------------------
__global__ __launch_bounds__(256) void bounds_k(const int* __restrict__ batch, int* __restrict__ bounds,
                                                int N, int B) {
    int i = blockIdx.x * 256 + threadIdx.x;
    if (i <= B) {
        int lo = 0, hi = N;
        while (lo < hi) { int m = (lo + hi) >> 1; if (batch[m] < i) lo = m + 1; else hi = m; }
        bounds[i] = lo;
    }
}

__global__ __launch_bounds__(128) void pool_part_k(const unsigned short* __restrict__ ge,
                                                   const int* __restrict__ bounds,
                                                   float* __restrict__ gemb) {
    int b = blockIdx.x >> 3;
    int s = blockIdx.x & 7;
    int start = bounds[b], end = bounds[b + 1];
    int len = end - start;
    int c0 = start + (int)(((long long)len * s) >> 3);
    int c1 = start + (int)(((long long)len * (s + 1)) >> 3);
    if (c1 <= c0) return;
    int col = threadIdx.x;
    float sum = 0.f;
    for (int n = c0; n < c1; ++n)
        sum += __uint_as_float((unsigned int)ge[(size_t)n * D_EMB + col] << 16);
    atomicAdd(&gemb[(size_t)b * D_EMB + col], sum);
}

// ---------------------------------------------------------------------------
// Node decoder: per-thread MLP [x fp32 | node_emb bf16](192) -> 32 -> 8 -> 1
// ---------------------------------------------------------------------------
__global__ __launch_bounds__(256) void node_dec_k(
    const float* __restrict__ x, const unsigned short* __restrict__ ne,
    const float* __restrict__ W1, const float* __restrict__ b1,
    const float* __restrict__ W2, const float* __restrict__ b2,
    const float* __restrict__ W3, const float* __restrict__ b3,
    float* __restrict__ out, int N) {
    __shared__ float W1s[GI * H1];
    __shared__ float W2s[H1 * H2];
    __shared__ float W3s[H2];
    __shared__ float b1s[H1], b2s[H2];
    for (int i = threadIdx.x; i < GI * H1; i += 256) W1s[i] = W1[i];
    if (threadIdx.x < H1 * H2) W2s[threadIdx.x] = W2[threadIdx.x];
    if (threadIdx.x < H2) { W3s[threadIdx.x] = W3[threadIdx.x]; b2s[threadIdx.x] = b2[threadIdx.x]; }
    if (threadIdx.x < H1) b1s[threadIdx.x] = b1[threadIdx.x];
    __syncthreads();
    int n = blockIdx.x * 256 + threadIdx.x;
    if (n >= N) return;
    float acc[H1];
    #pragma unroll
    for (int j = 0; j < H1; ++j) acc[j] = b1s[j];
    const float4* xr = (const float4*)(x + (size_t)n * D_IN);
    #pragma unroll 4
    for (int q = 0; q < D_IN / 4; ++q) {
        float4 v = xr[q];
        int k = q * 4;
        #pragma unroll
        for (int j = 0; j < H1; ++j) acc[j] = fmaf(v.x, W1s[(k + 0) * H1 + j], acc[j]);
        #pragma unroll
        for (int j = 0; j < H1; ++j) acc[j] = fmaf(v.y, W1s[(k + 1) * H1 + j], acc[j]);
        #pragma unroll
        for (int j = 0; j < H1; ++j) acc[j] = fmaf(v.z, W1s[(k + 2) * H1 + j], acc[j]);
        #pragma unroll
        for (int j = 0; j < H1; ++j) acc[j] = fmaf(v.w, W1s[(k + 3) * H1 + j], acc[j]);
    }
    const uint4* nr = (const uint4*)(ne + (size_t)n * D_EMB);
    #pragma unroll 4
    for (int q = 0; q < 16; ++q) {
        uint4 v = nr[q];
        float f[8] = {bflo(v.x), bfhi(v.x), bflo(v.y), bfhi(v.y),
                      bflo(v.z), bfhi(v.z), bflo(v.w), bfhi(v.w)};
        int k = D_IN + q * 8;
        #pragma unroll
        for (int e = 0; e < 8; ++e) {
            #pragma unroll
            for (int j = 0; j < H1; ++j) acc[j] = fmaf(f[e], W1s[(k + e) * H1 + j], acc[j]);
        }
    }
    #pragma unroll
    for (int j = 0; j < H1; ++j) acc[j] = fmaxf(acc[j], 0.f);
    float a2[H2];
    #pragma unroll
    for (int m = 0; m < H2; ++m) a2[m] = b2s[m];
    #pragma unroll
    for (int j = 0; j < H1; ++j)
        #pragma unroll
        for (int m = 0; m < H2; ++m) a2[m] = fmaf(acc[j], W2s[j * H2 + m], a2[m]);
    float o = b3[0];
    #pragma unroll
    for (int m = 0; m < H2; ++m) o = fmaf(fmaxf(a2[m], 0.f), W3s[m], o);
    out[n] = o;
}

// ---------------------------------------------------------------------------
// Graph decoder: mean-divide fused (reads summed gemb + bounds)
// ---------------------------------------------------------------------------
__global__ __launch_bounds__(256) void graph_dec_k(
    const float* __restrict__ gemb, const int* __restrict__ bounds,
    const float* __restrict__ W1, const float* __restrict__ b1,
    const float* __restrict__ W2, const float* __restrict__ b2,
    const float* __restrict__ W3, const float* __restrict__ b3,
    float* __restrict__ out, int B) {
    __shared__ float W1s[D_EMB * H1];
    __shared__ float W2s[H1 * H2];
    __shared__ float W3s[H2];
    __shared__ float b1s[H1], b2s[H2];
    for (int i = threadIdx.x; i < D_EMB * H1; i += 256) W1s[i] = W1[i];
    if (threadIdx.x < H1 * H2) W2s[threadIdx.x] = W2[threadIdx.x];
    if (threadIdx.x < H2) { W3s[threadIdx.x] = W3[threadIdx.x]; b2s[threadIdx.x] = b2[threadIdx.x]; }
    if (threadIdx.x < H1) b1s[threadIdx.x] = b1[threadIdx.x];
    __syncthreads();
    int gidx = threadIdx.x;
    if (gidx >= B) return;
    int len = bounds[gidx + 1] - bounds[gidx];
    float inv = 1.f / fmaxf((float)len, 1.f);
    float acc[H1];
    #pragma unroll
    for (int j = 0; j < H1; ++j) acc[j] = b1s[j];
    const float4* gr = (const float4*)(gemb + (size_t)gidx * D_EMB);
    for (int q = 0; q < D_EMB / 4; ++q) {
        float4 v = gr[q];
        v.x *= inv; v.y *= inv; v.z *= inv; v.w *= inv;
        int k = q * 4;
        #pragma unroll
        for (int j = 0; j < H1; ++j) acc[j] = fmaf(v.x, W1s[(k + 0) * H1 + j], acc[j]);
        #pragma unroll
        for (int j = 0; j < H1; ++j) acc[j] = fmaf(v.y, W1s[(k + 1) * H1 + j], acc[j]);
        #pragma unroll
        for (int j = 0; j < H1; ++j) acc[j] = fmaf(v.z, W1s[(k + 2) * H1 + j], acc[j]);
        #pragma unroll
        for (int j = 0; j < H1; ++j) acc[j] = fmaf(v.w, W1s[(k + 3) * H1 + j], acc[j]);
    }
    #pragma unroll
    for (int j = 0; j < H1; ++j) acc[j] = fmaxf(acc[j], 0.f);
    float a2[H2];
    #pragma unroll
    for (int m = 0; m < H2; ++m) a2[m] = b2s[m];
    #pragma unroll
    for (int j = 0; j < H1; ++j)
        #pragma unroll
        for (int m = 0; m < H2; ++m) a2[m] = fmaf(acc[j], W2s[j * H2 + m], a2[m]);
    float o = b3[0];
    #pragma unroll
    for (int m = 0; m < H2; ++m) o = fmaf(fmaxf(a2[m], 0.f), W3s[m], o);
    out[gidx] = o;
}

// ---------------------------------------------------------------------------
extern "C" void kernel_launch(void* const* d_in, const int* in_sizes, int n_in,
                              void* d_out, int out_size, void* d_ws, size_t ws_size,
                              hipStream_t stream) {
    const float* x       = (const float*)d_in[0];
    const int*   ei      = (const int*)d_in[1];
    const int*   batch   = (const int*)d_in[2];
    const float* W_in    = (const float*)d_in[3];
    const float* b_in    = (const float*)d_in[4];
    const float* eps     = (const float*)d_in[5];
    const float* mlp_W1  = (const float*)d_in[6];
    const float* mlp_b1  = (const float*)d_in[7];
    const float* mlp_W2  = (const float*)d_in[8];
    const float* mlp_b2  = (const float*)d_in[9];
    const float* ln_g    = (const float*)d_in[10];
    const float* ln_b    = (const float*)d_in[11];
    const float* out_W   = (const float*)d_in[12];
    const float* out_b   = (const float*)d_in[13];
    const float* lnf_g   = (const float*)d_in[14];
    const float* lnf_b   = (const float*)d_in[15];
    const float* graph_W = (const float*)d_in[16];
    const float* graph_b = (const float*)d_in[17];
    const float* gln_g   = (const float*)d_in[18];
    const float* gln_b   = (const float*)d_in[19];
    const float* dW1     = (const float*)d_in[20];
    const float* db1     = (const float*)d_in[21];
    const float* dW2     = (const float*)d_in[22];
    const float* db2     = (const float*)d_in[23];
    const float* dW3     = (const float*)d_in[24];
    const float* db3     = (const float*)d_in[25];
    const float* gW1     = (const float*)d_in[26];
    const float* gb1     = (const float*)d_in[27];
    const float* gW2     = (const float*)d_in[28];
    const float* gb2     = (const float*)d_in[29];
    const float* gW3     = (const float*)d_in[30];
    const float* gb3     = (const float*)d_in[31];
    float* out = (float*)d_out;

    const int N = in_sizes[0] / D_IN;
    const int E = in_sizes[1] / 2;
    const int B = out_size - N;
    const int N8 = (N + 7) / 8;

    const int* esrc = ei;
    const int* edst = ei + E;

    // workspace layout (~148 MB; rounds 2-6 used ~190 MB OK)
    size_t off = 0;
    auto alloc = [&](size_t bytes) { size_t o = off; off += (bytes + 255) & ~(size_t)255; return o; };
    char* ws = (char*)d_ws;
    unsigned short* xb    = (unsigned short*)(ws + alloc((size_t)N * D_IN * 2));
    unsigned short* hb0   = (unsigned short*)(ws + alloc((size_t)N * D_EMB * 2));
    unsigned short* hb1   = (unsigned short*)(ws + alloc((size_t)N * D_EMB * 2));
    unsigned short* zh    = (unsigned short*)(ws + alloc((size_t)N * D_EMB * 2));
    unsigned short* aggxb = (unsigned short*)(ws + alloc((size_t)N * D_IN * 2));
    unsigned short* zx0   = (unsigned short*)(ws + alloc((size_t)N * D_IN * 2));
    unsigned short* zx1   = (unsigned short*)(ws + alloc((size_t)N * D_IN * 2));
    unsigned short* zx2   = (unsigned short*)(ws + alloc((size_t)N * D_IN * 2));
    float* gemb = (float*)(ws + alloc((size_t)B * D_EMB * 4));
    unsigned short* wfpool = (unsigned short*)(ws + alloc((size_t)163840 * 2));
    int* row_ptr = (int*)(ws + alloc((size_t)(N + 1) * 4));
    int* cnt     = (int*)(ws + alloc((size_t)N * 4));
    int* bsum    = (int*)(ws + alloc(512 * 4));
    int* bounds  = (int*)(ws + alloc((size_t)(B + 1) * 4));
    int* csr     = (int*)(ws + alloc((size_t)E * 4));
    (void)ws_size;

    unsigned short* wf_in    = wfpool;
    unsigned short* wf_w1    = wf_in + (size_t)64 * 128;
    unsigned short* wf_w2    = wf_w1 + (size_t)3 * 192 * 128;
    unsigned short* wf_graph = wf_w2 + (size_t)3 * 128 * 128;
    unsigned short* wf_out   = wf_graph + (size_t)128 * 128;

    unsigned short* zxs[3] = {zx0, zx1, zx2};

    const int NB = (N + 255) / 256;
    const int gridEP = 8 * ((E + 1023) / 1024);
    const int gridN4 = (N + 3) / 4;
    const int gridG = (N + 127) / 128;

    // ---- CSR build (XCD-partitioned hist/scatter) ----
    hipMemsetAsync(cnt, 0, (size_t)N * 4, stream);
    hist_part_k<<<gridEP, 256, 0, stream>>>(edst, cnt, E, N8);
    scan1_k<<<NB, 256, 0, stream>>>(cnt, row_ptr, bsum, N);
    scan2_k<<<1, 512, 0, stream>>>(bsum, NB);
    scan3_k<<<(N + 256) / 256, 256, 0, stream>>>(row_ptr, bsum, cnt, N, E);
    scatter_part_k<<<gridEP, 256, 0, stream>>>(esrc, edst, cnt, csr, E, N8);

    // ---- prep ----
    xcvt_k<<<(N * D_IN / 4 + 255) / 256, 256, 0, stream>>>(x, xb, N * D_IN / 4);
    wfrag_all_k<<<640, 256, 0, stream>>>(W_in, mlp_W1, mlp_W2, graph_W, out_W,
                                         wf_in, wf_w1, wf_w2, wf_graph, wf_out);
    bounds_k<<<(B + 256) / 256, 256, 0, stream>>>(batch, bounds, N, B);
    hipMemsetAsync(gemb, 0, (size_t)B * D_EMB * 4, stream);

    // ---- x aggregation + per-layer zx precompute ----
    agg64b_k<<<(N + 7) / 8, 256, 0, stream>>>(xb, row_ptr, csr, aggxb, N);
    zxcvt_k<<<(N * 32 + 255) / 256, 256, 0, stream>>>(xb, aggxb, eps, zx0, zx1, zx2, N * 32);

    // ---- encoder ----
    enc_gemm_k<<<gridG, 256, 0, stream>>>(xb, wf_in, b_in, hb0, N);

    // ---- GIN layers ----
    unsigned short* hin = hb0;
    unsigned short* hout = hb1;
    for (int l = 0; l < 3; ++l) {
        aggz_k<<<gridN4, 256, 0, stream>>>(hin, row_ptr, csr, eps + l, zh, N);
        gin_layer_k<<<gridG, 256, 0, stream>>>(zxs[l], zh,
                                               wf_w1 + (size_t)l * 192 * 128, mlp_b1 + (size_t)l * D_EMB,
                                               wf_w2 + (size_t)l * 128 * 128, mlp_b2 + (size_t)l * D_EMB,
                                               ln_g + (size_t)l * D_EMB, ln_b + (size_t)l * D_EMB,
                                               hout, N);
        unsigned short* t = hin; hin = hout; hout = t;
    }
    // final h in hin (= hb1); hb0 and zh free
    unsigned short* zb  = hb0;
    unsigned short* neb = zh;

    // ---- both output branches in one pass over hin ----
    fc2_k<<<gridG, 256, 0, stream>>>(hin,
                                     wf_graph, graph_b, gln_g, gln_b, zb,
                                     wf_out, out_b, lnf_g, lnf_b, neb, N);
    pool_part_k<<<B * 8, 128, 0, stream>>>(zb, bounds, gemb);

    // ---- decoders ----
    node_dec_k<<<(N + 255) / 256, 256, 0, stream>>>(x, neb, dW1, db1, dW2, db2, dW3, db3, out, N);
    graph_dec_k<<<1, 256, 0, stream>>>(gemb, bounds, gW1, gb1, gW2, gb2, gW3, gb3, out + N, B);
}

// Round 12
// 828.328 us; speedup vs baseline: 1.1245x; 1.1245x over previous
//
#include <hip/hip_runtime.h>
#include <hip/hip_bf16.h>

#define D_IN 64
#define D_EMB 128
#define GI 192           // D_IN + D_EMB
#define H1 32
#define H2 8

typedef __attribute__((ext_vector_type(8))) short bf16x8;
typedef __attribute__((ext_vector_type(4))) float f32x4;

__device__ __forceinline__ unsigned short f2bf(float f) {
    unsigned int u = __float_as_uint(f);
    return (unsigned short)((u + 0x7fffu + ((u >> 16) & 1u)) >> 16);
}
__device__ __forceinline__ float bflo(unsigned int u) { return __uint_as_float(u << 16); }
__device__ __forceinline__ float bfhi(unsigned int u) { return __uint_as_float(u & 0xffff0000u); }
__device__ __forceinline__ unsigned int pk2(unsigned short a, unsigned short b) {
    return (unsigned int)a | ((unsigned int)b << 16);
}

// ---------------------------------------------------------------------------
// CSR build, XCD-partitioned (round-3 notes: merges partial-line writes in L2)
// ---------------------------------------------------------------------------
__global__ __launch_bounds__(256) void hist_part_k(const int* __restrict__ dst, int* __restrict__ cnt,
                                                   int E, int N8) {
    int p = blockIdx.x & 7;
    int base = (blockIdx.x >> 3) * 1024;
    int lo = p * N8, hi = lo + N8;
    #pragma unroll
    for (int t = 0; t < 4; ++t) {
        int e = base + t * 256 + threadIdx.x;
        if (e < E) {
            int d = dst[e];
            if (d >= lo && d < hi) atomicAdd(&cnt[d], 1);
        }
    }
}

__global__ __launch_bounds__(256) void scan1_k(const int* __restrict__ cnt, int* __restrict__ loc,
                                               int* __restrict__ bsum, int N) {
    __shared__ int s[256];
    int tid = threadIdx.x;
    int i = blockIdx.x * 256 + tid;
    int v = (i < N) ? cnt[i] : 0;
    s[tid] = v;
    __syncthreads();
    #pragma unroll
    for (int off = 1; off < 256; off <<= 1) {
        int u = (tid >= off) ? s[tid - off] : 0;
        __syncthreads();
        s[tid] += u;
        __syncthreads();
    }
    int incl = s[tid];
    if (i < N) loc[i] = incl - v;
    if (tid == 255) bsum[blockIdx.x] = incl;
}

__global__ __launch_bounds__(512) void scan2_k(int* __restrict__ bsum, int NB) {
    __shared__ int s[512];
    int tid = threadIdx.x;
    int v = (tid < NB) ? bsum[tid] : 0;
    s[tid] = v;
    __syncthreads();
    #pragma unroll
    for (int off = 1; off < 512; off <<= 1) {
        int u = (tid >= off) ? s[tid - off] : 0;
        __syncthreads();
        s[tid] += u;
        __syncthreads();
    }
    if (tid < NB) bsum[tid] = s[tid] - v;
}

__global__ __launch_bounds__(256) void scan3_k(int* __restrict__ rp, const int* __restrict__ bsum,
                                               int* __restrict__ cursor, int N, int E) {
    int i = blockIdx.x * 256 + threadIdx.x;
    if (i < N) {
        int r = rp[i] + bsum[i >> 8];
        rp[i] = r;
        cursor[i] = r;
    } else if (i == N) {
        rp[N] = E;
    }
}

__global__ __launch_bounds__(256) void scatter_part_k(const int* __restrict__ src, const int* __restrict__ dst,
                                                      int* __restrict__ cursor, int* __restrict__ csr,
                                                      int E, int N8) {
    int p = blockIdx.x & 7;
    int base = (blockIdx.x >> 3) * 1024;
    int lo = p * N8, hi = lo + N8;
    #pragma unroll
    for (int t = 0; t < 4; ++t) {
        int e = base + t * 256 + threadIdx.x;
        if (e < E) {
            int d = dst[e];
            if (d >= lo && d < hi) {
                int s = src[e];
                int pos = atomicAdd(&cursor[d], 1);
                csr[pos] = s;
            }
        }
    }
}

// ---------------------------------------------------------------------------
// Conversions / weight fragment prep
// ---------------------------------------------------------------------------
__global__ __launch_bounds__(256) void xcvt_k(const float* __restrict__ x, unsigned short* __restrict__ xb,
                                              int total4) {
    int i = blockIdx.x * 256 + threadIdx.x;
    if (i < total4) {
        float4 v = ((const float4*)x)[i];
        ((uint2*)xb)[i] = make_uint2(pk2(f2bf(v.x), f2bf(v.y)), pk2(f2bf(v.z), f2bf(v.w)));
    }
}

__global__ __launch_bounds__(256) void wfrag_all_k(
    const float* __restrict__ W_in, const float* __restrict__ mlp_W1, const float* __restrict__ mlp_W2,
    const float* __restrict__ graph_W, const float* __restrict__ out_W,
    unsigned short* __restrict__ wf_in, unsigned short* __restrict__ wf_w1,
    unsigned short* __restrict__ wf_w2, unsigned short* __restrict__ wf_graph,
    unsigned short* __restrict__ wf_out) {
    int idx = blockIdx.x * 256 + threadIdx.x;
    const float* src;
    unsigned short* dst;
    int local;
    if (idx < 8192) { src = W_in; dst = wf_in; local = idx; }
    else if (idx < 81920) { int t = idx - 8192; int l = t / 24576; local = t - l * 24576;
                            src = mlp_W1 + (size_t)l * 24576; dst = wf_w1 + (size_t)l * 24576; }
    else if (idx < 131072) { int t = idx - 81920; int l = t / 16384; local = t - l * 16384;
                             src = mlp_W2 + (size_t)l * 16384; dst = wf_w2 + (size_t)l * 16384; }
    else if (idx < 147456) { local = idx - 131072; src = graph_W; dst = wf_graph; }
    else { local = idx - 147456; src = out_W; dst = wf_out; }
    int k = local >> 7, c = local & 127;
    dst[(((size_t)(k >> 3) * 128) + c) * 8 + (k & 7)] = f2bf(src[local]);
}

// ---------------------------------------------------------------------------
// x aggregation (layer-invariant), bf16 output
// ---------------------------------------------------------------------------
__global__ __launch_bounds__(256) void agg64b_k(const unsigned short* __restrict__ xb,
                                                const int* __restrict__ rp, const int* __restrict__ cs,
                                                unsigned short* __restrict__ outb, int N) {
    int n = blockIdx.x * 8 + (threadIdx.x >> 5);
    int lane = threadIdx.x & 31;
    if (n >= N) return;
    int bg = rp[n], e = rp[n + 1];
    const unsigned int* x2 = (const unsigned int*)xb;
    float sx = 0.f, sy = 0.f;
    int j = bg;
    for (; j + 3 < e; j += 4) {
        unsigned int v0 = x2[(size_t)cs[j] * 32 + lane];
        unsigned int v1 = x2[(size_t)cs[j + 1] * 32 + lane];
        unsigned int v2 = x2[(size_t)cs[j + 2] * 32 + lane];
        unsigned int v3 = x2[(size_t)cs[j + 3] * 32 + lane];
        sx += bflo(v0) + bflo(v1) + bflo(v2) + bflo(v3);
        sy += bfhi(v0) + bfhi(v1) + bfhi(v2) + bfhi(v3);
    }
    for (; j < e; ++j) {
        unsigned int v = x2[(size_t)cs[j] * 32 + lane];
        sx += bflo(v);
        sy += bfhi(v);
    }
    ((unsigned int*)outb)[(size_t)n * 32 + lane] = pk2(f2bf(sx), f2bf(sy));
}

// ---------------------------------------------------------------------------
// Precompute zx_l = bf16((1+eps_l)*x + aggx) for all 3 layers ([N][64] each)
// ---------------------------------------------------------------------------
__global__ __launch_bounds__(256) void zxcvt_k(const unsigned short* __restrict__ xb,
                                               const unsigned short* __restrict__ aggxb,
                                               const float* __restrict__ eps,
                                               unsigned short* __restrict__ zx0,
                                               unsigned short* __restrict__ zx1,
                                               unsigned short* __restrict__ zx2, int total2) {
    int i = blockIdx.x * 256 + threadIdx.x;
    if (i >= total2) return;
    unsigned int xv = ((const unsigned int*)xb)[i];
    unsigned int av = ((const unsigned int*)aggxb)[i];
    float xl = bflo(xv), xh = bfhi(xv), al = bflo(av), ah = bfhi(av);
    float e0 = 1.0f + eps[0], e1 = 1.0f + eps[1], e2 = 1.0f + eps[2];
    ((unsigned int*)zx0)[i] = pk2(f2bf(fmaf(e0, xl, al)), f2bf(fmaf(e0, xh, ah)));
    ((unsigned int*)zx1)[i] = pk2(f2bf(fmaf(e1, xl, al)), f2bf(fmaf(e1, xh, ah)));
    ((unsigned int*)zx2)[i] = pk2(f2bf(fmaf(e2, xl, al)), f2bf(fmaf(e2, xh, ah)));
}

// ---------------------------------------------------------------------------
// h aggregation + GIN-z fold: zh = bf16((1+eps)*h[n] + sum_{neighbors} h)
// ---------------------------------------------------------------------------
__global__ __launch_bounds__(256) void aggz_k(const unsigned short* __restrict__ hb,
                                              const int* __restrict__ rp, const int* __restrict__ cs,
                                              const float* __restrict__ epsp,
                                              unsigned short* __restrict__ zh, int N) {
    int w = threadIdx.x >> 6, lane = threadIdx.x & 63;
    int n = blockIdx.x * 4 + w;
    if (n >= N) return;
    float es = 1.0f + epsp[0];
    int bg = rp[n], e = rp[n + 1];
    const unsigned int* h2 = (const unsigned int*)hb;
    float sx = 0.f, sy = 0.f;
    int j = bg;
    for (; j + 3 < e; j += 4) {
        unsigned int v0 = h2[(size_t)cs[j] * 64 + lane];
        unsigned int v1 = h2[(size_t)cs[j + 1] * 64 + lane];
        unsigned int v2 = h2[(size_t)cs[j + 2] * 64 + lane];
        unsigned int v3 = h2[(size_t)cs[j + 3] * 64 + lane];
        sx += bflo(v0) + bflo(v1) + bflo(v2) + bflo(v3);
        sy += bfhi(v0) + bfhi(v1) + bfhi(v2) + bfhi(v3);
    }
    for (; j < e; ++j) {
        unsigned int v = h2[(size_t)cs[j] * 64 + lane];
        sx += bflo(v);
        sy += bfhi(v);
    }
    unsigned int hv = h2[(size_t)n * 64 + lane];
    sx = fmaf(es, bflo(hv), sx);
    sy = fmaf(es, bfhi(hv), sy);
    ((unsigned int*)zh)[(size_t)n * 64 + lane] = pk2(f2bf(sx), f2bf(sy));
}

// ---------------------------------------------------------------------------
// Cross-wave LayerNorm epilogue for a 128x128 tile held as 4x4 16x16 C-frags.
// ---------------------------------------------------------------------------
template <int RELU, int ELU>
__device__ __forceinline__ void ln_epilogue(
    f32x4 (&acc)[4][4], const float* __restrict__ bias,
    const float* __restrict__ g, const float* __restrict__ b,
    unsigned short* __restrict__ out,
    int rowBase, int wr, int wc, int lg, int l15, int wh,
    float* rsum, float* rsq, int N) {
    float bv[4], gv[4], bbv[4];
    #pragma unroll
    for (int cb = 0; cb < 4; ++cb) {
        int col = wc + cb * 16 + l15;
        bv[cb] = bias[col];
        gv[cb] = g[col];
        bbv[cb] = b[col];
    }
    float ps[4][4], pq[4][4];
    #pragma unroll
    for (int rb = 0; rb < 4; ++rb)
        #pragma unroll
        for (int q = 0; q < 4; ++q) {
            float s = 0.f, sq = 0.f;
            #pragma unroll
            for (int cb = 0; cb < 4; ++cb) {
                float v = acc[rb][cb][q] + bv[cb];
                if (RELU) v = fmaxf(v, 0.f);
                s += v;
                sq += v * v;
            }
            ps[rb][q] = s;
            pq[rb][q] = sq;
        }
    #pragma unroll
    for (int m = 1; m < 16; m <<= 1) {
        #pragma unroll
        for (int rb = 0; rb < 4; ++rb)
            #pragma unroll
            for (int q = 0; q < 4; ++q) {
                ps[rb][q] += __shfl_xor(ps[rb][q], m, 64);
                pq[rb][q] += __shfl_xor(pq[rb][q], m, 64);
            }
    }
    if (l15 == 0) {
        #pragma unroll
        for (int rb = 0; rb < 4; ++rb)
            #pragma unroll
            for (int q = 0; q < 4; ++q) {
                int row = wr + rb * 16 + lg * 4 + q;
                rsum[wh * 128 + row] = ps[rb][q];
                rsq[wh * 128 + row] = pq[rb][q];
            }
    }
    __syncthreads();
    #pragma unroll
    for (int rb = 0; rb < 4; ++rb)
        #pragma unroll
        for (int q = 0; q < 4; ++q) {
            int row = wr + rb * 16 + lg * 4 + q;
            float st = rsum[row] + rsum[128 + row];
            float sqt = rsq[row] + rsq[128 + row];
            float mu = st * (1.f / 128.f);
            float var = sqt * (1.f / 128.f) - mu * mu;
            float rs = rsqrtf(var + 1e-5f);
            int grow = rowBase + row;
            if (grow < N) {
                #pragma unroll
                for (int cb = 0; cb < 4; ++cb) {
                    float v = acc[rb][cb][q] + bv[cb];
                    if (RELU) v = fmaxf(v, 0.f);
                    float y = (v - mu) * rs * gv[cb] + bbv[cb];
                    if (ELU) y = y > 0.f ? y : expm1f(y);
                    out[(size_t)grow * D_EMB + wc + cb * 16 + l15] = f2bf(y);
                }
            }
        }
}

// ---------------------------------------------------------------------------
// Encoder GEMM: full-A-stage (16 KB), 1 barrier, K=64
// ---------------------------------------------------------------------------
__global__ __launch_bounds__(256) void enc_gemm_k(
    const unsigned short* __restrict__ Abf, const unsigned short* __restrict__ Wf,
    const float* __restrict__ bias, unsigned short* __restrict__ C, int N) {
    __shared__ unsigned short AT[8 * 128 * 8];  // 16 KB
    const int tid = threadIdx.x;
    const int wid = tid >> 6, lane = tid & 63;
    const int l15 = lane & 15, lg = lane >> 4;
    const int rowBase = blockIdx.x * 128;
    const int wr = (wid >> 1) * 64, wc = (wid & 1) * 64;

    {
        int row = tid >> 1, half = tid & 1;
        int ar = min(rowBase + row, N - 1);
        const uint4* src = (const uint4*)(Abf + (size_t)ar * D_IN + half * 32);
        #pragma unroll
        for (int j = 0; j < 4; ++j) {
            int g = half * 4 + j;
            *(uint4*)&AT[(((size_t)g * 128) + row) * 8] = src[j];
        }
    }
    __syncthreads();

    f32x4 zero = {0.f, 0.f, 0.f, 0.f};
    f32x4 acc[4][4];
    #pragma unroll
    for (int i = 0; i < 4; ++i)
        #pragma unroll
        for (int j = 0; j < 4; ++j) acc[i][j] = zero;

    for (int k0 = 0; k0 < D_IN; k0 += 32) {
        const int G = (k0 >> 3) + lg;
        bf16x8 bfr[4];
        #pragma unroll
        for (int cb = 0; cb < 4; ++cb)
            bfr[cb] = *(const bf16x8*)&Wf[(((size_t)G * 128) + wc + cb * 16 + l15) * 8];
        #pragma unroll
        for (int rb = 0; rb < 4; ++rb) {
            bf16x8 afr = *(const bf16x8*)&AT[(((size_t)G * 128) + wr + rb * 16 + l15) * 8];
            #pragma unroll
            for (int cb = 0; cb < 4; ++cb)
                acc[rb][cb] = __builtin_amdgcn_mfma_f32_16x16x32_bf16(afr, bfr[cb], acc[rb][cb], 0, 0, 0);
        }
    }
    #pragma unroll
    for (int cb = 0; cb < 4; ++cb) {
        int col = wc + cb * 16 + l15;
        float bvv = bias[col];
        #pragma unroll
        for (int rb = 0; rb < 4; ++rb)
            #pragma unroll
            for (int q = 0; q < 4; ++q) {
                int row = rowBase + wr + rb * 16 + lg * 4 + q;
                if (row < N) C[(size_t)row * D_EMB + col] = f2bf(fmaxf(acc[rb][cb][q] + bvv, 0.f));
            }
    }
}

// ---------------------------------------------------------------------------
// Fused GIN layer v12: full-A-stage (48 KB: zx groups 0-7, zh groups 8-23),
// coalesced stage (2 threads/row), 1 barrier, 6 uninterrupted GEMM1 k-steps,
// T1 reuses first 32 KB, GEMM2, LN+ELU. Barriers 13 -> 4.
// ---------------------------------------------------------------------------
__global__ __launch_bounds__(256) void gin_layer_k(
    const unsigned short* __restrict__ zxl, const unsigned short* __restrict__ zhb,
    const unsigned short* __restrict__ W1f, const float* __restrict__ b1,
    const unsigned short* __restrict__ W2f, const float* __restrict__ b2,
    const float* __restrict__ lng, const float* __restrict__ lnb,
    unsigned short* __restrict__ hbo, int N) {
    __shared__ unsigned short AT[24 * 128 * 8];  // 48 KB; groups 0..15 reused as T1
    __shared__ float rsum[2 * 128];
    __shared__ float rsq[2 * 128];

    const int tid = threadIdx.x;
    const int wid = tid >> 6, lane = tid & 63;
    const int l15 = lane & 15, lg = lane >> 4;
    const int rowBase = blockIdx.x * 128;
    const int wr = (wid >> 1) * 64, wc = (wid & 1) * 64;
    const int wh = wid & 1;

    // ---- stage full A (192 cols/row, 2 threads per row, coalesced) ----
    {
        int row = tid >> 1, half = tid & 1;
        int ar = min(rowBase + row, N - 1);
        const uint4* sx = (const uint4*)(zxl + (size_t)ar * D_IN + half * 32);
        #pragma unroll
        for (int j = 0; j < 4; ++j) {
            int g = half * 4 + j;
            *(uint4*)&AT[(((size_t)g * 128) + row) * 8] = sx[j];
        }
        const uint4* sh = (const uint4*)(zhb + (size_t)ar * D_EMB + half * 64);
        #pragma unroll
        for (int j = 0; j < 8; ++j) {
            int g = 8 + half * 8 + j;
            *(uint4*)&AT[(((size_t)g * 128) + row) * 8] = sh[j];
        }
    }
    __syncthreads();

    f32x4 zero = {0.f, 0.f, 0.f, 0.f};
    f32x4 acc[4][4];
    #pragma unroll
    for (int i = 0; i < 4; ++i)
        #pragma unroll
        for (int j = 0; j < 4; ++j) acc[i][j] = zero;

    // ---- GEMM1: 6 k-steps, no barriers ----
    for (int k0 = 0; k0 < GI; k0 += 32) {
        const int G = (k0 >> 3) + lg;
        bf16x8 bfr[4];
        #pragma unroll
        for (int cb = 0; cb < 4; ++cb)
            bfr[cb] = *(const bf16x8*)&W1f[(((size_t)G * 128) + wc + cb * 16 + l15) * 8];
        #pragma unroll
        for (int rb = 0; rb < 4; ++rb) {
            bf16x8 afr = *(const bf16x8*)&AT[(((size_t)G * 128) + wr + rb * 16 + l15) * 8];
            #pragma unroll
            for (int cb = 0; cb < 4; ++cb)
                acc[rb][cb] = __builtin_amdgcn_mfma_f32_16x16x32_bf16(afr, bfr[cb], acc[rb][cb], 0, 0, 0);
        }
    }

    // ---- T1 write (reuse AT groups 0..15), GEMM2, LN ----
    __syncthreads();  // all A reads complete before overwrite
    #pragma unroll
    for (int cb = 0; cb < 4; ++cb) {
        int col = wc + cb * 16 + l15;
        float bvv = b1[col];
        #pragma unroll
        for (int rb = 0; rb < 4; ++rb)
            #pragma unroll
            for (int q = 0; q < 4; ++q) {
                int row = wr + rb * 16 + lg * 4 + q;
                float v = fmaxf(acc[rb][cb][q] + bvv, 0.f);
                AT[(((size_t)(col >> 3) * 128) + row) * 8 + (col & 7)] = f2bf(v);
            }
    }
    __syncthreads();

    f32x4 acc2[4][4];
    #pragma unroll
    for (int i = 0; i < 4; ++i)
        #pragma unroll
        for (int j = 0; j < 4; ++j) acc2[i][j] = zero;
    for (int k0 = 0; k0 < D_EMB; k0 += 32) {
        const int G = (k0 >> 3) + lg;
        bf16x8 bfr[4];
        #pragma unroll
        for (int cb = 0; cb < 4; ++cb)
            bfr[cb] = *(const bf16x8*)&W2f[(((size_t)G * 128) + wc + cb * 16 + l15) * 8];
        #pragma unroll
        for (int rb = 0; rb < 4; ++rb) {
            bf16x8 afr = *(const bf16x8*)&AT[(((size_t)G * 128) + wr + rb * 16 + l15) * 8];
            #pragma unroll
            for (int cb = 0; cb < 4; ++cb)
                acc2[rb][cb] = __builtin_amdgcn_mfma_f32_16x16x32_bf16(afr, bfr[cb], acc2[rb][cb], 0, 0, 0);
        }
    }

    ln_epilogue<0, 1>(acc2, b2, lng, lnb, hbo, rowBase, wr, wc, lg, l15, wh, rsum, rsq, N);
}

// ---------------------------------------------------------------------------
// Dual FC+LN v12: full-A-stage (32 KB), 1 barrier, both weight sets
// ---------------------------------------------------------------------------
__global__ __launch_bounds__(256) void fc2_k(
    const unsigned short* __restrict__ Abf,
    const unsigned short* __restrict__ WfG, const float* __restrict__ biasG,
    const float* __restrict__ gG, const float* __restrict__ bG, unsigned short* __restrict__ outG,
    const unsigned short* __restrict__ WfN, const float* __restrict__ biasN,
    const float* __restrict__ gN, const float* __restrict__ bN, unsigned short* __restrict__ outN,
    int N) {
    __shared__ unsigned short AT[16 * 128 * 8];  // 32 KB
    __shared__ float rsum[2 * 128];
    __shared__ float rsq[2 * 128];
    const int tid = threadIdx.x;
    const int wid = tid >> 6, lane = tid & 63;
    const int l15 = lane & 15, lg = lane >> 4;
    const int rowBase = blockIdx.x * 128;
    const int wr = (wid >> 1) * 64, wc = (wid & 1) * 64;
    const int wh = wid & 1;

    {
        int row = tid >> 1, half = tid & 1;
        int ar = min(rowBase + row, N - 1);
        const uint4* src = (const uint4*)(Abf + (size_t)ar * D_EMB + half * 64);
        #pragma unroll
        for (int j = 0; j < 8; ++j) {
            int g = half * 8 + j;
            *(uint4*)&AT[(((size_t)g * 128) + row) * 8] = src[j];
        }
    }
    __syncthreads();

    f32x4 zero = {0.f, 0.f, 0.f, 0.f};
    f32x4 accG[4][4], accN[4][4];
    #pragma unroll
    for (int i = 0; i < 4; ++i)
        #pragma unroll
        for (int j = 0; j < 4; ++j) { accG[i][j] = zero; accN[i][j] = zero; }

    for (int k0 = 0; k0 < D_EMB; k0 += 32) {
        const int G = (k0 >> 3) + lg;
        bf16x8 bfrG[4], bfrN[4];
        #pragma unroll
        for (int cb = 0; cb < 4; ++cb) {
            bfrG[cb] = *(const bf16x8*)&WfG[(((size_t)G * 128) + wc + cb * 16 + l15) * 8];
            bfrN[cb] = *(const bf16x8*)&WfN[(((size_t)G * 128) + wc + cb * 16 + l15) * 8];
        }
        #pragma unroll
        for (int rb = 0; rb < 4; ++rb) {
            bf16x8 afr = *(const bf16x8*)&AT[(((size_t)G * 128) + wr + rb * 16 + l15) * 8];
            #pragma unroll
            for (int cb = 0; cb < 4; ++cb) {
                accG[rb][cb] = __builtin_amdgcn_mfma_f32_16x16x32_bf16(afr, bfrG[cb], accG[rb][cb], 0, 0, 0);
                accN[rb][cb] = __builtin_amdgcn_mfma_f32_16x16x32_bf16(afr, bfrN[cb], accN[rb][cb], 0, 0, 0);
            }
        }
    }
    ln_epilogue<1, 0>(accG, biasG, gG, bG, outG, rowBase, wr, wc, lg, l15, wh, rsum, rsq, N);
    __syncthreads();
    ln_epilogue<1, 0>(accN, biasN, gN, bN, outN, rowBase, wr, wc, lg, l15, wh, rsum, rsq, N);
}

// ---------------------------------------------------------------------------
// Graph segment bounds, then 8-way-split mean pool
// ---------------------------------------------------------------------------
__global__ __launch_bounds__(256) void bounds_k(const int* __restrict__ batch, int* __restrict__ bounds,
                                                int N, int B) {
    int i = blockIdx.x * 256 + threadIdx.x;
    if (i <= B) {
        int lo = 0, hi = N;
        while (lo < hi) { int m = (lo + hi) >> 1; if (batch[m] < i) lo = m + 1; else hi = m; }
        bounds[i] = lo;
    }
}

__global__ __launch_bounds__(128) void pool_part_k(const unsigned short* __restrict__ ge,
                                                   const int* __restrict__ bounds,
                                                   float* __restrict__ gemb) {
    int b = blockIdx.x >> 3;
    int s = blockIdx.x & 7;
    int start = bounds[b], end = bounds[b + 1];
    int len = end - start;
    int c0 = start + (int)(((long long)len * s) >> 3);
    int c1 = start + (int)(((long long)len * (s + 1)) >> 3);
    if (c1 <= c0) return;
    int col = threadIdx.x;
    float sum = 0.f;
    for (int n = c0; n < c1; ++n)
        sum += __uint_as_float((unsigned int)ge[(size_t)n * D_EMB + col] << 16);
    atomicAdd(&gemb[(size_t)b * D_EMB + col], sum);
}

// ---------------------------------------------------------------------------
// Node decoder: per-thread MLP [x fp32 | node_emb bf16](192) -> 32 -> 8 -> 1
// ---------------------------------------------------------------------------
__global__ __launch_bounds__(256) void node_dec_k(
    const float* __restrict__ x, const unsigned short* __restrict__ ne,
    const float* __restrict__ W1, const float* __restrict__ b1,
    const float* __restrict__ W2, const float* __restrict__ b2,
    const float* __restrict__ W3, const float* __restrict__ b3,
    float* __restrict__ out, int N) {
    __shared__ float W1s[GI * H1];
    __shared__ float W2s[H1 * H2];
    __shared__ float W3s[H2];
    __shared__ float b1s[H1], b2s[H2];
    for (int i = threadIdx.x; i < GI * H1; i += 256) W1s[i] = W1[i];
    if (threadIdx.x < H1 * H2) W2s[threadIdx.x] = W2[threadIdx.x];
    if (threadIdx.x < H2) { W3s[threadIdx.x] = W3[threadIdx.x]; b2s[threadIdx.x] = b2[threadIdx.x]; }
    if (threadIdx.x < H1) b1s[threadIdx.x] = b1[threadIdx.x];
    __syncthreads();
    int n = blockIdx.x * 256 + threadIdx.x;
    if (n >= N) return;
    float acc[H1];
    #pragma unroll
    for (int j = 0; j < H1; ++j) acc[j] = b1s[j];
    const float4* xr = (const float4*)(x + (size_t)n * D_IN);
    #pragma unroll 4
    for (int q = 0; q < D_IN / 4; ++q) {
        float4 v = xr[q];
        int k = q * 4;
        #pragma unroll
        for (int j = 0; j < H1; ++j) acc[j] = fmaf(v.x, W1s[(k + 0) * H1 + j], acc[j]);
        #pragma unroll
        for (int j = 0; j < H1; ++j) acc[j] = fmaf(v.y, W1s[(k + 1) * H1 + j], acc[j]);
        #pragma unroll
        for (int j = 0; j < H1; ++j) acc[j] = fmaf(v.z, W1s[(k + 2) * H1 + j], acc[j]);
        #pragma unroll
        for (int j = 0; j < H1; ++j) acc[j] = fmaf(v.w, W1s[(k + 3) * H1 + j], acc[j]);
    }
    const uint4* nr = (const uint4*)(ne + (size_t)n * D_EMB);
    #pragma unroll 4
    for (int q = 0; q < 16; ++q) {
        uint4 v = nr[q];
        float f[8] = {bflo(v.x), bfhi(v.x), bflo(v.y), bfhi(v.y),
                      bflo(v.z), bfhi(v.z), bflo(v.w), bfhi(v.w)};
        int k = D_IN + q * 8;
        #pragma unroll
        for (int e = 0; e < 8; ++e) {
            #pragma unroll
            for (int j = 0; j < H1; ++j) acc[j] = fmaf(f[e], W1s[(k + e) * H1 + j], acc[j]);
        }
    }
    #pragma unroll
    for (int j = 0; j < H1; ++j) acc[j] = fmaxf(acc[j], 0.f);
    float a2[H2];
    #pragma unroll
    for (int m = 0; m < H2; ++m) a2[m] = b2s[m];
    #pragma unroll
    for (int j = 0; j < H1; ++j)
        #pragma unroll
        for (int m = 0; m < H2; ++m) a2[m] = fmaf(acc[j], W2s[j * H2 + m], a2[m]);
    float o = b3[0];
    #pragma unroll
    for (int m = 0; m < H2; ++m) o = fmaf(fmaxf(a2[m], 0.f), W3s[m], o);
    out[n] = o;
}

// ---------------------------------------------------------------------------
// Graph decoder: mean-divide fused (reads summed gemb + bounds)
// ---------------------------------------------------------------------------
__global__ __launch_bounds__(256) void graph_dec_k(
    const float* __restrict__ gemb, const int* __restrict__ bounds,
    const float* __restrict__ W1, const float* __restrict__ b1,
    const float* __restrict__ W2, const float* __restrict__ b2,
    const float* __restrict__ W3, const float* __restrict__ b3,
    float* __restrict__ out, int B) {
    __shared__ float W1s[D_EMB * H1];
    __shared__ float W2s[H1 * H2];
    __shared__ float W3s[H2];
    __shared__ float b1s[H1], b2s[H2];
    for (int i = threadIdx.x; i < D_EMB * H1; i += 256) W1s[i] = W1[i];
    if (threadIdx.x < H1 * H2) W2s[threadIdx.x] = W2[threadIdx.x];
    if (threadIdx.x < H2) { W3s[threadIdx.x] = W3[threadIdx.x]; b2s[threadIdx.x] = b2[threadIdx.x]; }
    if (threadIdx.x < H1) b1s[threadIdx.x] = b1[threadIdx.x];
    __syncthreads();
    int gidx = threadIdx.x;
    if (gidx >= B) return;
    int len = bounds[gidx + 1] - bounds[gidx];
    float inv = 1.f / fmaxf((float)len, 1.f);
    float acc[H1];
    #pragma unroll
    for (int j = 0; j < H1; ++j) acc[j] = b1s[j];
    const float4* gr = (const float4*)(gemb + (size_t)gidx * D_EMB);
    for (int q = 0; q < D_EMB / 4; ++q) {
        float4 v = gr[q];
        v.x *= inv; v.y *= inv; v.z *= inv; v.w *= inv;
        int k = q * 4;
        #pragma unroll
        for (int j = 0; j < H1; ++j) acc[j] = fmaf(v.x, W1s[(k + 0) * H1 + j], acc[j]);
        #pragma unroll
        for (int j = 0; j < H1; ++j) acc[j] = fmaf(v.y, W1s[(k + 1) * H1 + j], acc[j]);
        #pragma unroll
        for (int j = 0; j < H1; ++j) acc[j] = fmaf(v.z, W1s[(k + 2) * H1 + j], acc[j]);
        #pragma unroll
        for (int j = 0; j < H1; ++j) acc[j] = fmaf(v.w, W1s[(k + 3) * H1 + j], acc[j]);
    }
    #pragma unroll
    for (int j = 0; j < H1; ++j) acc[j] = fmaxf(acc[j], 0.f);
    float a2[H2];
    #pragma unroll
    for (int m = 0; m < H2; ++m) a2[m] = b2s[m];
    #pragma unroll
    for (int j = 0; j < H1; ++j)
        #pragma unroll
        for (int m = 0; m < H2; ++m) a2[m] = fmaf(acc[j], W2s[j * H2 + m], a2[m]);
    float o = b3[0];
    #pragma unroll
    for (int m = 0; m < H2; ++m) o = fmaf(fmaxf(a2[m], 0.f), W3s[m], o);
    out[gidx] = o;
}

// ---------------------------------------------------------------------------
extern "C" void kernel_launch(void* const* d_in, const int* in_sizes, int n_in,
                              void* d_out, int out_size, void* d_ws, size_t ws_size,
                              hipStream_t stream) {
    const float* x       = (const float*)d_in[0];
    const int*   ei      = (const int*)d_in[1];
    const int*   batch   = (const int*)d_in[2];
    const float* W_in    = (const float*)d_in[3];
    const float* b_in    = (const float*)d_in[4];
    const float* eps     = (const float*)d_in[5];
    const float* mlp_W1  = (const float*)d_in[6];
    const float* mlp_b1  = (const float*)d_in[7];
    const float* mlp_W2  = (const float*)d_in[8];
    const float* mlp_b2  = (const float*)d_in[9];
    const float* ln_g    = (const float*)d_in[10];
    const float* ln_b    = (const float*)d_in[11];
    const float* out_W   = (const float*)d_in[12];
    const float* out_b   = (const float*)d_in[13];
    const float* lnf_g   = (const float*)d_in[14];
    const float* lnf_b   = (const float*)d_in[15];
    const float* graph_W = (const float*)d_in[16];
    const float* graph_b = (const float*)d_in[17];
    const float* gln_g   = (const float*)d_in[18];
    const float* gln_b   = (const float*)d_in[19];
    const float* dW1     = (const float*)d_in[20];
    const float* db1     = (const float*)d_in[21];
    const float* dW2     = (const float*)d_in[22];
    const float* db2     = (const float*)d_in[23];
    const float* dW3     = (const float*)d_in[24];
    const float* db3     = (const float*)d_in[25];
    const float* gW1     = (const float*)d_in[26];
    const float* gb1     = (const float*)d_in[27];
    const float* gW2     = (const float*)d_in[28];
    const float* gb2     = (const float*)d_in[29];
    const float* gW3     = (const float*)d_in[30];
    const float* gb3     = (const float*)d_in[31];
    float* out = (float*)d_out;

    const int N = in_sizes[0] / D_IN;
    const int E = in_sizes[1] / 2;
    const int B = out_size - N;
    const int N8 = (N + 7) / 8;

    const int* esrc = ei;
    const int* edst = ei + E;

    // workspace layout
    size_t off = 0;
    auto alloc = [&](size_t bytes) { size_t o = off; off += (bytes + 255) & ~(size_t)255; return o; };
    char* ws = (char*)d_ws;
    unsigned short* xb    = (unsigned short*)(ws + alloc((size_t)N * D_IN * 2));
    unsigned short* hb0   = (unsigned short*)(ws + alloc((size_t)N * D_EMB * 2));
    unsigned short* hb1   = (unsigned short*)(ws + alloc((size_t)N * D_EMB * 2));
    unsigned short* zh    = (unsigned short*)(ws + alloc((size_t)N * D_EMB * 2));
    unsigned short* aggxb = (unsigned short*)(ws + alloc((size_t)N * D_IN * 2));
    unsigned short* zx0   = (unsigned short*)(ws + alloc((size_t)N * D_IN * 2));
    unsigned short* zx1   = (unsigned short*)(ws + alloc((size_t)N * D_IN * 2));
    unsigned short* zx2   = (unsigned short*)(ws + alloc((size_t)N * D_IN * 2));
    float* gemb = (float*)(ws + alloc((size_t)B * D_EMB * 4));
    unsigned short* wfpool = (unsigned short*)(ws + alloc((size_t)163840 * 2));
    int* row_ptr = (int*)(ws + alloc((size_t)(N + 1) * 4));
    int* cnt     = (int*)(ws + alloc((size_t)N * 4));
    int* bsum    = (int*)(ws + alloc(512 * 4));
    int* bounds  = (int*)(ws + alloc((size_t)(B + 1) * 4));
    int* csr     = (int*)(ws + alloc((size_t)E * 4));
    (void)ws_size;

    unsigned short* wf_in    = wfpool;
    unsigned short* wf_w1    = wf_in + (size_t)64 * 128;
    unsigned short* wf_w2    = wf_w1 + (size_t)3 * 192 * 128;
    unsigned short* wf_graph = wf_w2 + (size_t)3 * 128 * 128;
    unsigned short* wf_out   = wf_graph + (size_t)128 * 128;

    unsigned short* zxs[3] = {zx0, zx1, zx2};

    const int NB = (N + 255) / 256;
    const int gridEP = 8 * ((E + 1023) / 1024);
    const int gridN4 = (N + 3) / 4;
    const int gridG = (N + 127) / 128;

    // ---- CSR build (XCD-partitioned hist/scatter) ----
    hipMemsetAsync(cnt, 0, (size_t)N * 4, stream);
    hist_part_k<<<gridEP, 256, 0, stream>>>(edst, cnt, E, N8);
    scan1_k<<<NB, 256, 0, stream>>>(cnt, row_ptr, bsum, N);
    scan2_k<<<1, 512, 0, stream>>>(bsum, NB);
    scan3_k<<<(N + 256) / 256, 256, 0, stream>>>(row_ptr, bsum, cnt, N, E);
    scatter_part_k<<<gridEP, 256, 0, stream>>>(esrc, edst, cnt, csr, E, N8);

    // ---- prep ----
    xcvt_k<<<(N * D_IN / 4 + 255) / 256, 256, 0, stream>>>(x, xb, N * D_IN / 4);
    wfrag_all_k<<<640, 256, 0, stream>>>(W_in, mlp_W1, mlp_W2, graph_W, out_W,
                                         wf_in, wf_w1, wf_w2, wf_graph, wf_out);
    bounds_k<<<(B + 256) / 256, 256, 0, stream>>>(batch, bounds, N, B);
    hipMemsetAsync(gemb, 0, (size_t)B * D_EMB * 4, stream);

    // ---- x aggregation + per-layer zx precompute ----
    agg64b_k<<<(N + 7) / 8, 256, 0, stream>>>(xb, row_ptr, csr, aggxb, N);
    zxcvt_k<<<(N * 32 + 255) / 256, 256, 0, stream>>>(xb, aggxb, eps, zx0, zx1, zx2, N * 32);

    // ---- encoder ----
    enc_gemm_k<<<gridG, 256, 0, stream>>>(xb, wf_in, b_in, hb0, N);

    // ---- GIN layers ----
    unsigned short* hin = hb0;
    unsigned short* hout = hb1;
    for (int l = 0; l < 3; ++l) {
        aggz_k<<<gridN4, 256, 0, stream>>>(hin, row_ptr, csr, eps + l, zh, N);
        gin_layer_k<<<gridG, 256, 0, stream>>>(zxs[l], zh,
                                               wf_w1 + (size_t)l * 192 * 128, mlp_b1 + (size_t)l * D_EMB,
                                               wf_w2 + (size_t)l * 128 * 128, mlp_b2 + (size_t)l * D_EMB,
                                               ln_g + (size_t)l * D_EMB, ln_b + (size_t)l * D_EMB,
                                               hout, N);
        unsigned short* t = hin; hin = hout; hout = t;
    }
    // final h in hin (= hb1); hb0 and zh free
    unsigned short* zb  = hb0;
    unsigned short* neb = zh;

    // ---- both output branches in one pass over hin ----
    fc2_k<<<gridG, 256, 0, stream>>>(hin,
                                     wf_graph, graph_b, gln_g, gln_b, zb,
                                     wf_out, out_b, lnf_g, lnf_b, neb, N);
    pool_part_k<<<B * 8, 128, 0, stream>>>(zb, bounds, gemb);

    // ---- decoders ----
    node_dec_k<<<(N + 255) / 256, 256, 0, stream>>>(x, neb, dW1, db1, dW2, db2, dW3, db3, out, N);
    graph_dec_k<<<1, 256, 0, stream>>>(gemb, bounds, gW1, gb1, gW2, gb2, gW3, gb3, out + N, B);
}